// Round 27
// baseline (74.800 us; speedup 1.0000x reference)
//
#include <hip/hip_runtime.h>

// Problem constants: B=16, MAX_LEN=100, LOC_MAX=20000, EMB=256, D_DELTA=2
#define NB 16
#define MLEN 100
#define EMBD 256
#define LMAX 20000
#define LTILE 128           // l's per block (lane owns an l-pair)
#define NLT 157             // ceil(20000/128)
#define NKC 4               // K chunks of 32 m's (100 zero-padded to 128 in B)
#define FSTRIDE 520         // u16 per lsub sub-tile: 512 data + 8 pad (1040 B, 16B-aligned)
#define PREP_TASKS (NB * NKC * 16 * 64)   // 65536: (b,kc,etg,lane)

typedef __attribute__((ext_vector_type(4))) float f32x4;
typedef _Float16 f16x8 __attribute__((ext_vector_type(8)));

__device__ __forceinline__ unsigned short f2h(float x) {
    union { _Float16 f; unsigned short u; } a; a.f = (_Float16)x; return a.u;
}

// ---------------- Kernel 1: pack vwA = vw[m]*attn[b][m][e] into single-f16 MFMA B-fragments ----------------
// frag f = (b*NKC+kc)*16 + etg ; lane: e = etg*16 + (lane&15), k = (lane>>4)*8 + j, m = kc*32 + k
// m >= MLEN -> exact zero
__global__ __launch_bounds__(256)
void prep2_kernel(const float* __restrict__ attn, const float* __restrict__ vw,
                  unsigned short* __restrict__ Bf) {
    const int gid  = blockIdx.x * 256 + threadIdx.x;   // < 65536
    const int lane = gid & 63;
    const int f    = gid >> 6;
    const int etg  = f & 15;
    const int kcb  = f >> 4;
    const int kc   = kcb & 3;
    const int b    = kcb >> 2;
    const int e    = etg * 16 + (lane & 15);
    const int m0   = kc * 32 + (lane >> 4) * 8;
    unsigned h[8];
    #pragma unroll
    for (int j = 0; j < 8; ++j) {
        const int m = m0 + j;
        float x = 0.f;
        if (m < MLEN) x = vw[m] * attn[((size_t)b * MLEN + m) * EMBD + e];
        h[j] = f2h(x);
    }
    uint4 hi = make_uint4(h[0]|(h[1]<<16), h[2]|(h[3]<<16), h[4]|(h[5]<<16), h[6]|(h[7]<<16));
    reinterpret_cast<uint4*>(Bf)[gid] = hi;
}

// ---------------- Kernel 2: single-pass f16 GEMM, LTILE=128, TRUE 2-phase-deep A prefetch ----------------
// Block: (b, 128 l's), 4 waves; wave w owns e-range [w*64,+64). K = 100 m's in 4 chunks of 32.
// Pipeline (per kc): writeA(kc) [counted wait, slot q] -> loadB(kc+1) [BEFORE issueA: Bn's
// dependency wait at the Bc=Bn copy becomes vmcnt(8), NOT 0] -> issueA(kc+2) [newest: survives
// the copy's wait and the barrier -> genuine 2-phase latency cover] -> raw s_barrier (lgkmcnt
// only, no vmcnt drain) -> 32 MFMA vs reg-B -> Bc=Bn [vmcnt(8): sdelta prefetch stays in flight].
__global__ __launch_bounds__(256, 2)
void main_kernel(const unsigned short* __restrict__ Bf,
                 const float* __restrict__ sdelta, const float* __restrict__ embt,
                 float* __restrict__ out) {
    __shared__ __align__(16) unsigned short AhL[2][8 * FSTRIDE];  // 2 x 8320 B
    __shared__ float red[512];                                    // 2048 B (total 18688 B)

    const int b    = blockIdx.x;
    const int lt0  = blockIdx.y;
    const int l0   = lt0 * LTILE;
    const int w    = threadIdx.x >> 6;
    const int lane = threadIdx.x & 63;
    const int llo  = lane & 15;
    const int lhi  = lane >> 4;

    f32x4 acc[8][4];
    #pragma unroll
    for (int lt = 0; lt < 8; ++lt)
        #pragma unroll
        for (int et = 0; et < 4; ++et)
            acc[lt][et] = (f32x4){0.f, 0.f, 0.f, 0.f};

    // per-lane global source: 2 consecutive l's (one f32x4), clamped for the edge tile
    const int lcl = min(l0 + 2 * lane, LMAX - 2);

    f32x4 vA[2][8];
    // wave w loads rows r32 = w*8 + jj (8 consecutive rows), each lane its l-pair (16B coalesced)
    auto issueA = [&](int kc) {
        const int q = kc & 1;
        #pragma unroll
        for (int jj = 0; jj < 8; ++jj) {
            const int m  = kc * 32 + w * 8 + jj;
            const int mc = (m < MLEN) ? m : (MLEN - 1);
            vA[q][jj] = *reinterpret_cast<const f32x4*>(
                            sdelta + ((size_t)(b * MLEN + mc) * LMAX + lcl) * 2);
        }
    };
    // pair-sum -> f16; lane's 8 j-elements contiguous -> 2 x ds_write_b128 (l even, l odd)
    auto writeA = [&](int kc) {
        const int q   = kc & 1;
        const int lt  = lane >> 3;          // lsub of this lane's l-pair
        const int lo0 = (2 * lane) & 15;    // row (l) within 16-tile, even
        unsigned h0[8], h1[8];
        #pragma unroll
        for (int jj = 0; jj < 8; ++jj) {
            const int m = kc * 32 + w * 8 + jj;
            const float msk = (m < MLEN) ? 1.f : 0.f;
            const f32x4 v = vA[q][jj];
            h0[jj] = f2h((v[0] + v[1]) * msk);
            h1[jj] = f2h((v[2] + v[3]) * msk);
        }
        const int i0 = lt * FSTRIDE + (lo0 | (w << 4)) * 8;   // kg == w
        *reinterpret_cast<uint4*>(&AhL[q][i0]) =
            make_uint4(h0[0]|(h0[1]<<16), h0[2]|(h0[3]<<16), h0[4]|(h0[5]<<16), h0[6]|(h0[7]<<16));
        *reinterpret_cast<uint4*>(&AhL[q][i0 + 8]) =
            make_uint4(h1[0]|(h1[1]<<16), h1[2]|(h1[3]<<16), h1[4]|(h1[5]<<16), h1[6]|(h1[7]<<16));
    };
    auto loadB = [&](int kc, f16x8* dst) {
        #pragma unroll
        for (int et = 0; et < 4; ++et) {
            const size_t bo = (((size_t)(b * NKC + kc) * 16 + (w * 4 + et)) * 64 + lane) * 8;
            dst[et] = *reinterpret_cast<const f16x8*>(Bf + bo);
        }
    };

    f16x8 Bc[4], Bn[4];
    issueA(0);                                   // slot 0 in flight
    issueA(1);                                   // slot 1 in flight
    loadB(0, Bc);
    #pragma unroll
    for (int kc = 0; kc < NKC; ++kc) {
        const int q = kc & 1;
        writeA(kc);                              // counted wait on slot q only (2-phase-old loads)
        if (kc + 1 < NKC) loadB(kc + 1, Bn);     // B FIRST: its wait won't drain the A prefetch
        __builtin_amdgcn_sched_barrier(0);
        if (kc + 2 < NKC) issueA(kc + 2);        // A prefetch NEWEST: survives Bc=Bn's vmcnt(8)
        __builtin_amdgcn_sched_barrier(0);
        asm volatile("s_waitcnt lgkmcnt(0)" ::: "memory");
        __builtin_amdgcn_sched_barrier(0);
        __builtin_amdgcn_s_barrier();            // raw barrier: no vmcnt drain
        __builtin_amdgcn_sched_barrier(0);

        #pragma unroll
        for (int lt = 0; lt < 8; ++lt) {
            const f16x8 ah = *reinterpret_cast<const f16x8*>(&AhL[q][lt * FSTRIDE + lane * 8]);
            #pragma unroll
            for (int et = 0; et < 4; ++et)
                acc[lt][et] = __builtin_amdgcn_mfma_f32_16x16x32_f16(ah, Bc[et], acc[lt][et], 0, 0, 0);
        }
        if (kc + 1 < NKC) { Bc[0] = Bn[0]; Bc[1] = Bn[1]; Bc[2] = Bn[2]; Bc[3] = Bn[3]; }
        // no second barrier: buf q next written at kc+2, ordered by kc+1's barrier (r13/r16-verified)
    }

    // ---------------- epilogue: p[l] = sum_e G[l,e] * E[1+l, e] ----------------
    // C/D layout: col = lane&15 (e), row = (lane>>4)*4 + i (l)  [verified r1-r26]
    float p[8][4];
    #pragma unroll
    for (int lt = 0; lt < 8; ++lt) {
        #pragma unroll
        for (int i = 0; i < 4; ++i) {
            const int l  = l0 + lt * 16 + lhi * 4 + i;
            const int lc = (l < LMAX) ? l : (LMAX - 1);
            const float* Er = embt + (size_t)(1 + lc) * EMBD + w * 64 + llo;
            float s = acc[lt][0][i] * Er[0];
            s += acc[lt][1][i] * Er[16];
            s += acc[lt][2][i] * Er[32];
            s += acc[lt][3][i] * Er[48];
            p[lt][i] = s;
        }
    }
    #pragma unroll
    for (int lt = 0; lt < 8; ++lt)
        #pragma unroll
        for (int i = 0; i < 4; ++i) {
            float x = p[lt][i];
            x += __shfl_xor(x, 1);
            x += __shfl_xor(x, 2);
            x += __shfl_xor(x, 4);
            x += __shfl_xor(x, 8);
            p[lt][i] = x;
        }
    if (llo == 0) {
        #pragma unroll
        for (int lt = 0; lt < 8; ++lt)
            *reinterpret_cast<float4*>(&red[w * 128 + lt * 16 + lhi * 4]) =
                make_float4(p[lt][0], p[lt][1], p[lt][2], p[lt][3]);
    }
    __syncthreads();
    if (threadIdx.x < 128) {
        const int t = threadIdx.x;
        const int l = l0 + t;
        if (l < LMAX) {
            out[(size_t)b * LMAX + l] = red[t] + red[128 + t] + red[256 + t] + red[384 + t];
        }
    }
}

// ---------------- Fallback (ws too small): straightforward f32 compute ----------------
__global__ __launch_bounds__(256)
void fallback_kernel(const float* __restrict__ attn, const float* __restrict__ sdelta,
                     const float* __restrict__ embt, const float* __restrict__ vw,
                     float* __restrict__ out) {
    const int idx = blockIdx.x * 256 + threadIdx.x;
    if (idx >= NB * LMAX) return;
    const int b = idx / LMAX;
    const int l = idx % LMAX;
    float s = 0.f;
    for (int m = 0; m < MLEN; ++m) {
        const float* ar = attn + ((size_t)b * MLEN + m) * EMBD;
        const float* er = embt + (size_t)(l + 1) * EMBD;
        float dot = 0.f;
        for (int e = 0; e < EMBD; ++e) dot += ar[e] * er[e];
        const size_t so = (((size_t)b * MLEN + m) * LMAX + l) * 2;
        s += dot * vw[m] * (sdelta[so] + sdelta[so + 1]);
    }
    out[idx] = s;
}

extern "C" void kernel_launch(void* const* d_in, const int* in_sizes, int n_in,
                              void* d_out, int out_size, void* d_ws, size_t ws_size,
                              hipStream_t stream) {
    const float* attn   = (const float*)d_in[0];  // [16][100][256] f32
    const float* sdelta = (const float*)d_in[1];  // [16][100][20000][2] f32
    // d_in[2] = traj_len — unused by the reference computation
    const float* embt   = (const float*)d_in[3];  // [20001][256] f32
    const float* vw     = (const float*)d_in[4];  // [1][100] f32
    float* out = (float*)d_out;                   // [16][20000] f32

    const size_t fragShorts = (size_t)PREP_TASKS * 8;                // 524288 u16
    const size_t needed     = fragShorts * sizeof(unsigned short);   // 1 MB

    if (ws_size >= needed) {
        unsigned short* Bf = (unsigned short*)d_ws;
        prep2_kernel<<<PREP_TASKS / 256, 256, 0, stream>>>(attn, vw, Bf);
        main_kernel<<<dim3(NB, NLT), 256, 0, stream>>>(Bf, sdelta, embt, out);
    } else {
        fallback_kernel<<<(NB * LMAX + 255) / 256, 256, 0, stream>>>(attn, sdelta, embt, vw, out);
    }
}

// Round 28
// 72.154 us; speedup vs baseline: 1.0367x; 1.0367x over previous
//
#include <hip/hip_runtime.h>

// Problem constants: B=16, MAX_LEN=100, LOC_MAX=20000, EMB=256, D_DELTA=2
#define NB 16
#define MLEN 100
#define EMBD 256
#define LMAX 20000
#define LTILE 128           // l's per block (lane owns an l-pair)
#define NLT 157             // ceil(20000/128)
#define NKC 4               // K chunks of 32 m's (100 zero-padded to 128 in B)
#define FSTRIDE 520         // u16 per lsub sub-tile: 512 data + 8 pad (1040 B, 16B-aligned)
#define PREP_TASKS (NB * NKC * 16 * 64)   // 65536: (b,kc,etg,lane)

typedef __attribute__((ext_vector_type(4))) float f32x4;
typedef _Float16 f16x8 __attribute__((ext_vector_type(8)));

__device__ __forceinline__ unsigned short f2h(float x) {
    union { _Float16 f; unsigned short u; } a; a.f = (_Float16)x; return a.u;
}

// ---------------- Kernel 1: pack vwA = vw[m]*attn[b][m][e] into single-f16 MFMA B-fragments ----------------
// frag f = (b*NKC+kc)*16 + etg ; lane: e = etg*16 + (lane&15), k = (lane>>4)*8 + j, m = kc*32 + k
// m >= MLEN -> exact zero
__global__ __launch_bounds__(256)
void prep2_kernel(const float* __restrict__ attn, const float* __restrict__ vw,
                  unsigned short* __restrict__ Bf) {
    const int gid  = blockIdx.x * 256 + threadIdx.x;   // < 65536
    const int lane = gid & 63;
    const int f    = gid >> 6;
    const int etg  = f & 15;
    const int kcb  = f >> 4;
    const int kc   = kcb & 3;
    const int b    = kcb >> 2;
    const int e    = etg * 16 + (lane & 15);
    const int m0   = kc * 32 + (lane >> 4) * 8;
    unsigned h[8];
    #pragma unroll
    for (int j = 0; j < 8; ++j) {
        const int m = m0 + j;
        float x = 0.f;
        if (m < MLEN) x = vw[m] * attn[((size_t)b * MLEN + m) * EMBD + e];
        h[j] = f2h(x);
    }
    uint4 hi = make_uint4(h[0]|(h[1]<<16), h[2]|(h[3]<<16), h[4]|(h[5]<<16), h[6]|(h[7]<<16));
    reinterpret_cast<uint4*>(Bf)[gid] = hi;
}

// ---------------- Kernel 2: single-pass f16 GEMM, LTILE=128, 2-phase-deep A prefetch ----------------
// Block: (b, 128 l's), 4 waves; wave w owns e-range [w*64,+64). K = 100 m's in 4 chunks of 32.
// Pipeline (per kc): writeA(kc) [consumes slot q] -> issueA(kc+2) into freed slot q [BEFORE the
// barrier: ~2 phases of latency cover] -> raw s_barrier (lgkmcnt only, no vmcnt drain) ->
// loadB(kc+1) -> 32 MFMA vs reg-B. vA[2] slots. (Verified best: r18/r24/r26, 72.4 us.)
__global__ __launch_bounds__(256, 2)
void main_kernel(const unsigned short* __restrict__ Bf,
                 const float* __restrict__ sdelta, const float* __restrict__ embt,
                 float* __restrict__ out) {
    __shared__ __align__(16) unsigned short AhL[2][8 * FSTRIDE];  // 2 x 8320 B
    __shared__ float red[512];                                    // 2048 B (total 18688 B)

    const int b    = blockIdx.x;
    const int lt0  = blockIdx.y;
    const int l0   = lt0 * LTILE;
    const int w    = threadIdx.x >> 6;
    const int lane = threadIdx.x & 63;
    const int llo  = lane & 15;
    const int lhi  = lane >> 4;

    f32x4 acc[8][4];
    #pragma unroll
    for (int lt = 0; lt < 8; ++lt)
        #pragma unroll
        for (int et = 0; et < 4; ++et)
            acc[lt][et] = (f32x4){0.f, 0.f, 0.f, 0.f};

    // per-lane global source: 2 consecutive l's (one f32x4), clamped for the edge tile
    const int lcl = min(l0 + 2 * lane, LMAX - 2);

    f32x4 vA[2][8];
    // wave w loads rows r32 = w*8 + jj (8 consecutive rows), each lane its l-pair (16B coalesced)
    auto issueA = [&](int kc) {
        const int q = kc & 1;
        #pragma unroll
        for (int jj = 0; jj < 8; ++jj) {
            const int m  = kc * 32 + w * 8 + jj;
            const int mc = (m < MLEN) ? m : (MLEN - 1);
            vA[q][jj] = *reinterpret_cast<const f32x4*>(
                            sdelta + ((size_t)(b * MLEN + mc) * LMAX + lcl) * 2);
        }
    };
    // pair-sum -> f16; lane's 8 j-elements contiguous -> 2 x ds_write_b128 (l even, l odd)
    auto writeA = [&](int kc) {
        const int q   = kc & 1;
        const int lt  = lane >> 3;          // lsub of this lane's l-pair
        const int lo0 = (2 * lane) & 15;    // row (l) within 16-tile, even
        unsigned h0[8], h1[8];
        #pragma unroll
        for (int jj = 0; jj < 8; ++jj) {
            const int m = kc * 32 + w * 8 + jj;
            const float msk = (m < MLEN) ? 1.f : 0.f;
            const f32x4 v = vA[q][jj];
            h0[jj] = f2h((v[0] + v[1]) * msk);
            h1[jj] = f2h((v[2] + v[3]) * msk);
        }
        const int i0 = lt * FSTRIDE + (lo0 | (w << 4)) * 8;   // kg == w
        *reinterpret_cast<uint4*>(&AhL[q][i0]) =
            make_uint4(h0[0]|(h0[1]<<16), h0[2]|(h0[3]<<16), h0[4]|(h0[5]<<16), h0[6]|(h0[7]<<16));
        *reinterpret_cast<uint4*>(&AhL[q][i0 + 8]) =
            make_uint4(h1[0]|(h1[1]<<16), h1[2]|(h1[3]<<16), h1[4]|(h1[5]<<16), h1[6]|(h1[7]<<16));
    };
    auto loadB = [&](int kc, f16x8* dst) {
        #pragma unroll
        for (int et = 0; et < 4; ++et) {
            const size_t bo = (((size_t)(b * NKC + kc) * 16 + (w * 4 + et)) * 64 + lane) * 8;
            dst[et] = *reinterpret_cast<const f16x8*>(Bf + bo);
        }
    };

    f16x8 Bc[4], Bn[4];
    issueA(0);                                   // slot 0 in flight
    issueA(1);                                   // slot 1 in flight
    loadB(0, Bc);
    #pragma unroll
    for (int kc = 0; kc < NKC; ++kc) {
        const int q = kc & 1;
        writeA(kc);                              // counted wait on slot q only (2-phase-old loads)
        if (kc + 2 < NKC) issueA(kc + 2);        // refill freed slot q BEFORE barrier: 2-phase cover
        __builtin_amdgcn_sched_barrier(0);
        asm volatile("s_waitcnt lgkmcnt(0)" ::: "memory");
        __builtin_amdgcn_sched_barrier(0);
        __builtin_amdgcn_s_barrier();            // raw barrier: no vmcnt drain
        __builtin_amdgcn_sched_barrier(0);

        if (kc + 1 < NKC) loadB(kc + 1, Bn);     // B prefetch (L2-resident) during MFMA window
        __builtin_amdgcn_sched_barrier(0);

        #pragma unroll
        for (int lt = 0; lt < 8; ++lt) {
            const f16x8 ah = *reinterpret_cast<const f16x8*>(&AhL[q][lt * FSTRIDE + lane * 8]);
            #pragma unroll
            for (int et = 0; et < 4; ++et)
                acc[lt][et] = __builtin_amdgcn_mfma_f32_16x16x32_f16(ah, Bc[et], acc[lt][et], 0, 0, 0);
        }
        if (kc + 1 < NKC) { Bc[0] = Bn[0]; Bc[1] = Bn[1]; Bc[2] = Bn[2]; Bc[3] = Bn[3]; }
        // no second barrier: buf q next written at kc+2, ordered by kc+1's barrier (r13/r16-verified)
    }

    // ---------------- epilogue: p[l] = sum_e G[l,e] * E[1+l, e] ----------------
    // C/D layout: col = lane&15 (e), row = (lane>>4)*4 + i (l)  [verified r1-r27]
    float p[8][4];
    #pragma unroll
    for (int lt = 0; lt < 8; ++lt) {
        #pragma unroll
        for (int i = 0; i < 4; ++i) {
            const int l  = l0 + lt * 16 + lhi * 4 + i;
            const int lc = (l < LMAX) ? l : (LMAX - 1);
            const float* Er = embt + (size_t)(1 + lc) * EMBD + w * 64 + llo;
            float s = acc[lt][0][i] * Er[0];
            s += acc[lt][1][i] * Er[16];
            s += acc[lt][2][i] * Er[32];
            s += acc[lt][3][i] * Er[48];
            p[lt][i] = s;
        }
    }
    #pragma unroll
    for (int lt = 0; lt < 8; ++lt)
        #pragma unroll
        for (int i = 0; i < 4; ++i) {
            float x = p[lt][i];
            x += __shfl_xor(x, 1);
            x += __shfl_xor(x, 2);
            x += __shfl_xor(x, 4);
            x += __shfl_xor(x, 8);
            p[lt][i] = x;
        }
    if (llo == 0) {
        #pragma unroll
        for (int lt = 0; lt < 8; ++lt)
            *reinterpret_cast<float4*>(&red[w * 128 + lt * 16 + lhi * 4]) =
                make_float4(p[lt][0], p[lt][1], p[lt][2], p[lt][3]);
    }
    __syncthreads();
    if (threadIdx.x < 128) {
        const int t = threadIdx.x;
        const int l = l0 + t;
        if (l < LMAX) {
            out[(size_t)b * LMAX + l] = red[t] + red[128 + t] + red[256 + t] + red[384 + t];
        }
    }
}

// ---------------- Fallback (ws too small): straightforward f32 compute ----------------
__global__ __launch_bounds__(256)
void fallback_kernel(const float* __restrict__ attn, const float* __restrict__ sdelta,
                     const float* __restrict__ embt, const float* __restrict__ vw,
                     float* __restrict__ out) {
    const int idx = blockIdx.x * 256 + threadIdx.x;
    if (idx >= NB * LMAX) return;
    const int b = idx / LMAX;
    const int l = idx % LMAX;
    float s = 0.f;
    for (int m = 0; m < MLEN; ++m) {
        const float* ar = attn + ((size_t)b * MLEN + m) * EMBD;
        const float* er = embt + (size_t)(l + 1) * EMBD;
        float dot = 0.f;
        for (int e = 0; e < EMBD; ++e) dot += ar[e] * er[e];
        const size_t so = (((size_t)b * MLEN + m) * LMAX + l) * 2;
        s += dot * vw[m] * (sdelta[so] + sdelta[so + 1]);
    }
    out[idx] = s;
}

extern "C" void kernel_launch(void* const* d_in, const int* in_sizes, int n_in,
                              void* d_out, int out_size, void* d_ws, size_t ws_size,
                              hipStream_t stream) {
    const float* attn   = (const float*)d_in[0];  // [16][100][256] f32
    const float* sdelta = (const float*)d_in[1];  // [16][100][20000][2] f32
    // d_in[2] = traj_len — unused by the reference computation
    const float* embt   = (const float*)d_in[3];  // [20001][256] f32
    const float* vw     = (const float*)d_in[4];  // [1][100] f32
    float* out = (float*)d_out;                   // [16][20000] f32

    const size_t fragShorts = (size_t)PREP_TASKS * 8;                // 524288 u16
    const size_t needed     = fragShorts * sizeof(unsigned short);   // 1 MB

    if (ws_size >= needed) {
        unsigned short* Bf = (unsigned short*)d_ws;
        prep2_kernel<<<PREP_TASKS / 256, 256, 0, stream>>>(attn, vw, Bf);
        main_kernel<<<dim3(NB, NLT), 256, 0, stream>>>(Bf, sdelta, embt, out);
    } else {
        fallback_kernel<<<(NB * LMAX + 255) / 256, 256, 0, stream>>>(attn, sdelta, embt, vw, out);
    }
}